// Round 3
// baseline (62.832 us; speedup 1.0000x reference)
//
#include <hip/hip_runtime.h>

// SeparationLoss: landmarks [B=1024, N=256, D=2] fp32 -> scalar fp32
//   sum_b sum_{i<j} d2 * exp(-d2/25),  d2 = ||x_i - x_j||^2
//
// Circular pairing: thread i pairs with (i+j) mod 256, j=1..127 (each
// unordered pair exactly once) + j=128 at weight 0.5 (each such pair hit
// twice). Split per batch into 2 blocks (j in [1,64] / [65,128]) -> 2048
// blocks, 8 blocks/CU = 32 waves/CU for latency hiding.
// R2 BUG FIXED: loop now covers exactly j = base..base+62; epilogue does
// base+63 with weight (half ? 0.5 : 1.0). R2 gave j=128 weight 1.5.
// LDS duplicate kills the modulo; stride-8B lane access = 2-way alias = free.
// exp(-d2/25) = exp2(C*d2) -> single v_exp_f32.

#define N_PTS 256
#define EXP2_C (-0.057707801635558534f)  // -log2(e)/25

__device__ __forceinline__ float fast_exp2(float x) {
#if __has_builtin(__builtin_amdgcn_exp2f)
    return __builtin_amdgcn_exp2f(x);
#else
    return exp2f(x);
#endif
}

__device__ __forceinline__ float pair_term(float xi, float yi, float2 q) {
    float dx = xi - q.x, dy = yi - q.y;
    float d2 = dx * dx + dy * dy;
    return d2 * fast_exp2(EXP2_C * d2);
}

__global__ __launch_bounds__(256, 8) void sep_main(
    const float* __restrict__ lm, float* __restrict__ partial) {
    __shared__ float2 pts[2 * N_PTS];
    const int bid = blockIdx.x;
    const int b = bid >> 1;
    const int half = bid & 1;
    const int t = threadIdx.x;

    const float2* src = (const float2*)(lm + (size_t)b * N_PTS * 2);
    float2 p = src[t];          // coalesced 8B/lane
    pts[t] = p;
    pts[t + N_PTS] = p;         // duplicate: kills the modulo
    __syncthreads();

    const float xi = p.x, yi = p.y;
    const float2* row = &pts[t];
    const int base = 1 + 64 * half;   // 1 or 65

    float s0 = 0.f, s1 = 0.f, s2 = 0.f, s3 = 0.f;
    for (int j = base; j < base + 60; j += 4) {   // j = base..base+59
        s0 += pair_term(xi, yi, row[j]);
        s1 += pair_term(xi, yi, row[j + 1]);
        s2 += pair_term(xi, yi, row[j + 2]);
        s3 += pair_term(xi, yi, row[j + 3]);
    }
    s0 += pair_term(xi, yi, row[base + 60]);
    s1 += pair_term(xi, yi, row[base + 61]);
    s2 += pair_term(xi, yi, row[base + 62]);
    {   // j = base+63: 64 (weight 1) for half 0, 128 (weight 0.5) for half 1
        const float w = half ? 0.5f : 1.0f;
        s3 += w * pair_term(xi, yi, row[base + 63]);
    }

    float s = (s0 + s1) + (s2 + s3);
    for (int off = 32; off > 0; off >>= 1) s += __shfl_down(s, off, 64);

    __shared__ float wsum[4];
    if ((t & 63) == 0) wsum[t >> 6] = s;
    __syncthreads();
    if (t == 0) partial[bid] = (wsum[0] + wsum[1]) + (wsum[2] + wsum[3]);
}

__global__ __launch_bounds__(256) void sep_reduce(
    const float* __restrict__ partial, float* __restrict__ out) {
    const int t = threadIdx.x;
    const float4* p4 = (const float4*)partial;   // 2048 floats = 512 float4
    float4 a = p4[t];
    float4 b = p4[t + 256];
    float s = ((a.x + a.y) + (a.z + a.w)) + ((b.x + b.y) + (b.z + b.w));
    for (int off = 32; off > 0; off >>= 1) s += __shfl_down(s, off, 64);
    __shared__ float wsum[4];
    if ((t & 63) == 0) wsum[t >> 6] = s;
    __syncthreads();
    if (t == 0) out[0] = (wsum[0] + wsum[1]) + (wsum[2] + wsum[3]);
}

extern "C" void kernel_launch(void* const* d_in, const int* in_sizes, int n_in,
                              void* d_out, int out_size, void* d_ws, size_t ws_size,
                              hipStream_t stream) {
    const float* landmarks = (const float*)d_in[0];
    float* out = (float*)d_out;
    float* partial = (float*)d_ws;               // 2048 floats = 8 KB

    const int B = in_sizes[0] / (N_PTS * 2);     // 1024

    sep_main<<<2 * B, N_PTS, 0, stream>>>(landmarks, partial);
    sep_reduce<<<1, N_PTS, 0, stream>>>(partial, out);
}